// Round 2
// baseline (6603.822 us; speedup 1.0000x reference)
//
#include <hip/hip_runtime.h>
#include <hip/hip_bf16.h>
#include <math.h>

#define NPOS 81920   // 512*8*4*5
#define CDIM 256
#define NHEAD 16
#define DHEAD 16
#define SIGMA 1e-4f
#define LEAK 0.2f
#define BCHUNK 64            // batch elements per chunk
#define MROWS (BCHUNK * 160) // 10240 rows per chunk

typedef __hip_bfloat16 bf16;

__device__ __forceinline__ float ldf(const float* p) { return *p; }
__device__ __forceinline__ float ldf(const bf16* p) { return __bfloat162float(*p); }
__device__ __forceinline__ void stf(float* p, float v) { *p = v; }
__device__ __forceinline__ void stf(bf16* p, float v) { *p = __float2bfloat16(v); }

// ---------------- encoder: h = tanh([x+sigma*noise, rand] @ W_enc) + pos_emb ----------------
__global__ void encode_kernel(const float* __restrict__ x, const float* __restrict__ noise,
                              const float* __restrict__ rnd, const float* __restrict__ We,
                              const float* __restrict__ pe, bf16* __restrict__ H) {
    int p = blockIdx.x;
    int c = threadIdx.x;
    float a = x[p] + SIGMA * noise[p];
    float b = rnd[p];
    float v = tanhf(a * We[c] + b * We[CDIM + c]) + pe[(p % 160) * CDIM + c];
    H[(size_t)p * CDIM + c] = __float2bfloat16(v);
}

// ---------------- Hn = bo[l,0] + bo[l,1] + bo[l,2] broadcast ----------------
__global__ void biasinit_kernel(const float* __restrict__ bo, bf16* __restrict__ Hn) {
    int p = blockIdx.x;
    int c = threadIdx.x;
    Hn[(size_t)p * CDIM + c] = __float2bfloat16(bo[c] + bo[CDIM + c] + bo[2 * CDIM + c]);
}

// ---------------- tiled GEMM: C[M x N] (+)= A[M x K] @ B[K x N] ----------------
// 64x64 block tile, BK=16, 256 threads, 4x4 micro-tile per thread.
// mode: 0 = store, 1 = accumulate, 2 = accumulate + leaky-relu
template <typename AT, typename CT>
__global__ __launch_bounds__(256) void gemm_t(const AT* __restrict__ A,
                                              const float* __restrict__ B,
                                              CT* __restrict__ C,
                                              int N, int K, int mode) {
    __shared__ float As[16][64];
    __shared__ float Bs[16][64];
    int tid = threadIdx.x;
    int bm = blockIdx.y * 64;
    int bn = blockIdx.x * 64;
    int tr = tid >> 4;    // 0..15
    int tc = tid & 15;    // 0..15
    float acc[4][4] = {};
    for (int k0 = 0; k0 < K; k0 += 16) {
#pragma unroll
        for (int i = 0; i < 4; i++) {
            int r = (tid >> 4) + i * 16;  // 0..63
            int c = tid & 15;             // 0..15
            As[c][r] = ldf(&A[(size_t)(bm + r) * K + k0 + c]);
        }
#pragma unroll
        for (int i = 0; i < 4; i++) {
            int r = (tid >> 6) + i * 4;   // 0..15
            int c = tid & 63;             // 0..63
            Bs[r][c] = B[(size_t)(k0 + r) * N + bn + c];
        }
        __syncthreads();
#pragma unroll
        for (int kk = 0; kk < 16; kk++) {
            float a[4], b[4];
#pragma unroll
            for (int i = 0; i < 4; i++) a[i] = As[kk][tr * 4 + i];
#pragma unroll
            for (int j = 0; j < 4; j++) b[j] = Bs[kk][tc * 4 + j];
#pragma unroll
            for (int i = 0; i < 4; i++)
#pragma unroll
                for (int j = 0; j < 4; j++)
                    acc[i][j] += a[i] * b[j];
        }
        __syncthreads();
    }
#pragma unroll
    for (int i = 0; i < 4; i++) {
        int row = bm + tr * 4 + i;
#pragma unroll
        for (int j = 0; j < 4; j++) {
            int col = bn + tc * 4 + j;
            size_t idx = (size_t)row * N + col;
            float v = acc[i][j];
            if (mode >= 1) v += ldf(&C[idx]);
            if (mode == 2) v = v >= 0.f ? v : LEAK * v;
            stf(&C[idx], v);
        }
    }
}

// ---------------- per-sequence axial attention (chunk-local, f32 Q/KV) ----------------
// One block per sequence. Writes attention output back over Q rows (disjoint across blocks).
__global__ __launch_bounds__(256) void attn_kernel(const float* __restrict__ Q,
                                                   const float* __restrict__ KV,
                                                   float* __restrict__ AO, int axis) {
    __shared__ float qs[8][CDIM];
    __shared__ float ks[8][CDIM];
    __shared__ float vs[8][CDIM];
    __shared__ float sm[NHEAD][8][8];
    int tid = threadIdx.x;
    int seq = blockIdx.x;
    int T, stride, base;
    if (axis == 0) {        // i varies (dim 8), fixed (b, j, k)
        T = 8; stride = 20;
        int b = seq / 20, r = seq % 20;
        base = b * 160 + r;
    } else if (axis == 1) { // j varies (dim 4), fixed (b, i, k)
        T = 4; stride = 5;
        int b = seq / 40, r = seq % 40;
        base = b * 160 + (r / 5) * 20 + (r % 5);
    } else {                // k varies (dim 5), fixed (b, i, j)
        T = 5; stride = 1;
        int b = seq / 32, r = seq % 32;
        base = b * 160 + r * 5;
    }
    for (int t = 0; t < T; t++) {
        int p = base + t * stride;
        qs[t][tid] = Q[(size_t)p * CDIM + tid];
        ks[t][tid] = KV[(size_t)p * 512 + tid];
        vs[t][tid] = KV[(size_t)p * 512 + 256 + tid];
    }
    __syncthreads();
    int hh = tid >> 4;  // head 0..15
    int d  = tid & 15;  // 0..15
    for (int idx = d; idx < T * T; idx += 16) {
        int t = idx / T, s = idx % T;
        float a = 0.f;
#pragma unroll
        for (int dd = 0; dd < DHEAD; dd++)
            a += qs[t][hh * 16 + dd] * ks[s][hh * 16 + dd];
        sm[hh][t][s] = a * 0.25f;  // * DH^-0.5
    }
    __syncthreads();
    if (d < T) {
        float m = -1e30f;
        for (int s = 0; s < T; s++) m = fmaxf(m, sm[hh][d][s]);
        float sum = 0.f;
        for (int s = 0; s < T; s++) { float e = expf(sm[hh][d][s] - m); sm[hh][d][s] = e; sum += e; }
        float inv = 1.f / sum;
        for (int s = 0; s < T; s++) sm[hh][d][s] *= inv;
    }
    __syncthreads();
    for (int t = 0; t < T; t++) {
        float a = 0.f;
        for (int s = 0; s < T; s++) a += sm[hh][t][s] * vs[s][hh * 16 + d];
        int p = base + t * stride;
        AO[(size_t)p * CDIM + hh * 16 + d] = a;
    }
}

// ---------------- decoder: out = sigmoid(H @ Wd + bd) ----------------
__global__ void decode_kernel(const bf16* __restrict__ H, const float* __restrict__ Wd,
                              const float* __restrict__ bd, float* __restrict__ out) {
    int tid = threadIdx.x;
    int pos = blockIdx.x * 4 + (tid >> 6);
    int lane = tid & 63;
    float acc = 0.f;
#pragma unroll
    for (int q = 0; q < 4; q++) {
        int c = lane + q * 64;
        acc += __bfloat162float(H[(size_t)pos * CDIM + c]) * Wd[c];
    }
#pragma unroll
    for (int off = 32; off > 0; off >>= 1) acc += __shfl_down(acc, off);
    if (lane == 0) out[pos] = 1.f / (1.f + expf(-(acc + bd[0])));
}

extern "C" void kernel_launch(void* const* d_in, const int* in_sizes, int n_in,
                              void* d_out, int out_size, void* d_ws, size_t ws_size,
                              hipStream_t stream) {
    const float* x     = (const float*)d_in[0];
    const float* noise = (const float*)d_in[1];
    const float* rnd   = (const float*)d_in[2];
    const float* We    = (const float*)d_in[3];
    const float* pe    = (const float*)d_in[4];
    const float* Wq    = (const float*)d_in[5];
    const float* Wkv   = (const float*)d_in[6];
    const float* Wo    = (const float*)d_in[7];
    const float* bo    = (const float*)d_in[8];
    const float* Wd    = (const float*)d_in[9];
    const float* bd    = (const float*)d_in[10];
    float* out = (float*)d_out;

    // workspace layout: H bf16 | Hn bf16 | Qc f32 (chunk) | KVc f32 (chunk)  ≈ 115 MB
    bf16* H   = (bf16*)d_ws;
    bf16* Hn  = H + (size_t)NPOS * CDIM;
    float* Qc  = (float*)(Hn + (size_t)NPOS * CDIM);
    float* KVc = Qc + (size_t)MROWS * CDIM;

    encode_kernel<<<NPOS, 256, 0, stream>>>(x, noise, rnd, We, pe, H);

    for (int l = 0; l < 2; l++) {
        biasinit_kernel<<<NPOS, 256, 0, stream>>>(bo + (size_t)l * 3 * CDIM, Hn);
        for (int a = 0; a < 3; a++) {
            const float* wq  = Wq  + (size_t)(l * 3 + a) * CDIM * CDIM;
            const float* wkv = Wkv + (size_t)(l * 3 + a) * CDIM * 512;
            const float* wo  = Wo  + (size_t)(l * 3 + a) * CDIM * CDIM;
            int nseq = (a == 0) ? BCHUNK * 20 : (a == 1) ? BCHUNK * 40 : BCHUNK * 32;
            for (int ch = 0; ch < NPOS / (MROWS); ch++) {
                const bf16* Hc = H + (size_t)ch * MROWS * CDIM;
                bf16* Hnc = Hn + (size_t)ch * MROWS * CDIM;
                dim3 gq(CDIM / 64, MROWS / 64);
                dim3 gkv(512 / 64, MROWS / 64);
                gemm_t<bf16, float><<<gq,  256, 0, stream>>>(Hc, wq,  Qc,  CDIM, CDIM, 0);
                gemm_t<bf16, float><<<gkv, 256, 0, stream>>>(Hc, wkv, KVc, 512,  CDIM, 0);
                attn_kernel<<<nseq, 256, 0, stream>>>(Qc, KVc, Qc, a);
                gemm_t<float, bf16><<<gq, 256, 0, stream>>>(Qc, wo, Hnc, CDIM, CDIM, (a == 2) ? 2 : 1);
            }
        }
        bf16* tmp = H; H = Hn; Hn = tmp;
    }

    decode_kernel<<<NPOS / 4, 256, 0, stream>>>(H, Wd, bd, out);
}

// Round 3
// 1268.147 us; speedup vs baseline: 5.2075x; 5.2075x over previous
//
#include <hip/hip_runtime.h>
#include <hip/hip_bf16.h>
#include <math.h>

#define NPOS 81920   // 512*8*4*5
#define CDIM 256
#define SIGMA 1e-4f
#define LEAK 0.2f

typedef __hip_bfloat16 bf16;
typedef __bf16 bf16x8 __attribute__((ext_vector_type(8)));
typedef float f32x4 __attribute__((ext_vector_type(4)));

// ---------------- encoder: h = tanh([x+sigma*noise, rand] @ W_enc) + pos_emb ----------------
__global__ void encode_kernel(const float* __restrict__ x, const float* __restrict__ noise,
                              const float* __restrict__ rnd, const float* __restrict__ We,
                              const float* __restrict__ pe, bf16* __restrict__ H) {
    int p = blockIdx.x;
    int c = threadIdx.x;
    float a = x[p] + SIGMA * noise[p];
    float b = rnd[p];
    float v = tanhf(a * We[c] + b * We[CDIM + c]) + pe[(p % 160) * CDIM + c];
    H[(size_t)p * CDIM + c] = __float2bfloat16(v);
}

// ---------------- Hn = bo[l,0]+bo[l,1]+bo[l,2] broadcast ----------------
__global__ void biasinit_kernel(const float* __restrict__ bo, bf16* __restrict__ Hn) {
    int p = blockIdx.x;
    int c = threadIdx.x;
    Hn[(size_t)p * CDIM + c] = __float2bfloat16(bo[c] + bo[CDIM + c] + bo[2 * CDIM + c]);
}

// ---------------- weight pack: B^T bf16 ----------------
// QKV: out[mat][n][k], n<256 -> Wq[mat][k][n], else Wkv[mat][k][n-256]   (6 mats, n<768, k<256)
__global__ void pack_qkv_kernel(const float* __restrict__ Wq, const float* __restrict__ Wkv,
                                bf16* __restrict__ out) {
    int mat = blockIdx.x / 768;
    int n = blockIdx.x % 768;
    int k = threadIdx.x;
    float v = (n < 256) ? Wq[(size_t)mat * 65536 + (size_t)k * 256 + n]
                        : Wkv[(size_t)mat * 131072 + (size_t)k * 512 + (n - 256)];
    out[(size_t)blockIdx.x * 256 + k] = __float2bfloat16(v);
}
// Wo: out[mat][n][k] = Wo[mat][k][n]   (6 mats, n<256, k<256)
__global__ void pack_wo_kernel(const float* __restrict__ Wo, bf16* __restrict__ out) {
    int mat = blockIdx.x / 256;
    int n = blockIdx.x % 256;
    int k = threadIdx.x;
    out[(size_t)blockIdx.x * 256 + k] =
        __float2bfloat16(Wo[(size_t)mat * 65536 + (size_t)k * 256 + n]);
}

// ---------------- bf16 MFMA GEMM (m97-style): C[M x N] (+)= A[M x 256] @ B^T[N x 256]^T --------
// 128x128 tile, BK=32, 256 threads (4 waves, 2x2 of 64x64), 16x16x32_bf16 MFMA, K=256 fixed.
// mode: 0 = store, 1 = accumulate into C (bf16 RMW), 2 = accumulate + leaky-relu
__global__ __launch_bounds__(256) void gemm_mfma(const bf16* __restrict__ A, int lda,
                                                 const bf16* __restrict__ Bt,
                                                 bf16* __restrict__ C, int ldc, int mode) {
    __shared__ __bf16 Asb[128 * 32];
    __shared__ __bf16 Bsb[128 * 32];
    int tid = threadIdx.x;
    int wave = tid >> 6, lane = tid & 63;
    int quad = lane >> 4, m = lane & 15;
    int bm = blockIdx.y * 128, bn = blockIdx.x * 128;
    int wr = (wave >> 1) * 64, wc = (wave & 1) * 64;
    f32x4 acc[4][4] = {};

    for (int k0 = 0; k0 < 256; k0 += 32) {
        // stage A tile [128][32] and B^T tile [128][32]; chunk = 16 B = 8 bf16
#pragma unroll
        for (int rep = 0; rep < 2; rep++) {
            int ch = rep * 256 + wave * 64 + lane;
            int row = ch >> 2, c16 = ch & 3;
            __builtin_amdgcn_global_load_lds(
                (const __attribute__((address_space(1))) void*)(A + (size_t)(bm + row) * lda + k0 + c16 * 8),
                (__attribute__((address_space(3))) void*)(Asb + (rep * 256 + wave * 64) * 8),
                16, 0, 0);
        }
#pragma unroll
        for (int rep = 0; rep < 2; rep++) {
            int ch = rep * 256 + wave * 64 + lane;
            int row = ch >> 2, c16 = ch & 3;
            __builtin_amdgcn_global_load_lds(
                (const __attribute__((address_space(1))) void*)(Bt + (size_t)(bn + row) * 256 + k0 + c16 * 8),
                (__attribute__((address_space(3))) void*)(Bsb + (rep * 256 + wave * 64) * 8),
                16, 0, 0);
        }
        __syncthreads();
        bf16x8 af[4], bf_[4];
#pragma unroll
        for (int i = 0; i < 4; i++)
            af[i] = *(const bf16x8*)(Asb + (wr + i * 16 + m) * 32 + quad * 8);
#pragma unroll
        for (int j = 0; j < 4; j++)
            bf_[j] = *(const bf16x8*)(Bsb + (wc + j * 16 + m) * 32 + quad * 8);
#pragma unroll
        for (int i = 0; i < 4; i++)
#pragma unroll
            for (int j = 0; j < 4; j++)
                acc[i][j] = __builtin_amdgcn_mfma_f32_16x16x32_bf16(af[i], bf_[j], acc[i][j], 0, 0, 0);
        __syncthreads();
    }

    // epilogue: C/D layout col = lane&15, row = quad*4 + r
#pragma unroll
    for (int i = 0; i < 4; i++) {
#pragma unroll
        for (int j = 0; j < 4; j++) {
#pragma unroll
            for (int r = 0; r < 4; r++) {
                int row = bm + wr + i * 16 + quad * 4 + r;
                int col = bn + wc + j * 16 + m;
                size_t idx = (size_t)row * ldc + col;
                float v = acc[i][j][r];
                if (mode >= 1) v += __bfloat162float(C[idx]);
                if (mode == 2) v = v >= 0.f ? v : LEAK * v;
                C[idx] = __float2bfloat16(v);
            }
        }
    }
}

// ---------------- per-sequence axial attention over QKV buffer (bf16, row stride 768) --------
// q at [p*768 + c], k at [+256], v at [+512]; output written back over q slot.
__global__ __launch_bounds__(256) void attn_kernel(bf16* __restrict__ QKV, int axis) {
    __shared__ float qs[8][CDIM];
    __shared__ float ks[8][CDIM];
    __shared__ float vs[8][CDIM];
    __shared__ float sm[16][8][8];
    int tid = threadIdx.x;
    int seq = blockIdx.x;
    int T, stride, base;
    if (axis == 0) {        // i varies (dim 8)
        T = 8; stride = 20;
        int b = seq / 20, r = seq % 20;
        base = b * 160 + r;
    } else if (axis == 1) { // j varies (dim 4)
        T = 4; stride = 5;
        int b = seq / 40, r = seq % 40;
        base = b * 160 + (r / 5) * 20 + (r % 5);
    } else {                // k varies (dim 5)
        T = 5; stride = 1;
        int b = seq / 32, r = seq % 32;
        base = b * 160 + r * 5;
    }
    for (int t = 0; t < T; t++) {
        size_t p = (size_t)(base + t * stride) * 768;
        qs[t][tid] = __bfloat162float(QKV[p + tid]);
        ks[t][tid] = __bfloat162float(QKV[p + 256 + tid]);
        vs[t][tid] = __bfloat162float(QKV[p + 512 + tid]);
    }
    __syncthreads();
    int hh = tid >> 4;
    int d  = tid & 15;
    for (int idx = d; idx < T * T; idx += 16) {
        int t = idx / T, s = idx % T;
        float a = 0.f;
#pragma unroll
        for (int dd = 0; dd < 16; dd++)
            a += qs[t][hh * 16 + dd] * ks[s][hh * 16 + dd];
        sm[hh][t][s] = a * 0.25f;
    }
    __syncthreads();
    if (d < T) {
        float mx = -1e30f;
        for (int s = 0; s < T; s++) mx = fmaxf(mx, sm[hh][d][s]);
        float sum = 0.f;
        for (int s = 0; s < T; s++) { float e = expf(sm[hh][d][s] - mx); sm[hh][d][s] = e; sum += e; }
        float inv = 1.f / sum;
        for (int s = 0; s < T; s++) sm[hh][d][s] *= inv;
    }
    __syncthreads();
    for (int t = 0; t < T; t++) {
        float a = 0.f;
        for (int s = 0; s < T; s++) a += sm[hh][t][s] * vs[s][hh * 16 + d];
        QKV[(size_t)(base + t * stride) * 768 + hh * 16 + d] = __float2bfloat16(a);
    }
}

// ---------------- decoder: out = sigmoid(H @ Wd + bd) ----------------
__global__ void decode_kernel(const bf16* __restrict__ H, const float* __restrict__ Wd,
                              const float* __restrict__ bd, float* __restrict__ out) {
    int tid = threadIdx.x;
    int pos = blockIdx.x * 4 + (tid >> 6);
    int lane = tid & 63;
    float acc = 0.f;
#pragma unroll
    for (int q = 0; q < 4; q++) {
        int c = lane + q * 64;
        acc += __bfloat162float(H[(size_t)pos * CDIM + c]) * Wd[c];
    }
#pragma unroll
    for (int off = 32; off > 0; off >>= 1) acc += __shfl_down(acc, off);
    if (lane == 0) out[pos] = 1.f / (1.f + expf(-(acc + bd[0])));
}

extern "C" void kernel_launch(void* const* d_in, const int* in_sizes, int n_in,
                              void* d_out, int out_size, void* d_ws, size_t ws_size,
                              hipStream_t stream) {
    const float* x     = (const float*)d_in[0];
    const float* noise = (const float*)d_in[1];
    const float* rnd   = (const float*)d_in[2];
    const float* We    = (const float*)d_in[3];
    const float* pe    = (const float*)d_in[4];
    const float* Wq    = (const float*)d_in[5];
    const float* Wkv   = (const float*)d_in[6];
    const float* Wo    = (const float*)d_in[7];
    const float* bo    = (const float*)d_in[8];
    const float* Wd    = (const float*)d_in[9];
    const float* bd    = (const float*)d_in[10];
    float* out = (float*)d_out;

    // ws layout (all bf16): H | Hn | WqkvT | WoT | QKV(chunk)
    bf16* H     = (bf16*)d_ws;
    bf16* Hn    = H + (size_t)NPOS * CDIM;
    bf16* WqkvT = Hn + (size_t)NPOS * CDIM;
    bf16* WoT   = WqkvT + (size_t)6 * 768 * 256;
    bf16* QKV   = WoT + (size_t)6 * 256 * 256;

    // adaptive M-chunking so QKV chunk fits ws_size (round-1 evidence: ws >= 115 MB)
    size_t fixed = ((size_t)NPOS * CDIM * 2 + (size_t)6 * 768 * 256 + (size_t)6 * 256 * 256) * 2;
    int c = 1;
    while (c < 8 && fixed + (size_t)(NPOS / c) * 768 * 2 > ws_size) c <<= 1;
    int mc = NPOS / c;  // rows per chunk: multiple of 160 and 128 for c in {1,2,4,8}

    pack_qkv_kernel<<<6 * 768, 256, 0, stream>>>(Wq, Wkv, WqkvT);
    pack_wo_kernel<<<6 * 256, 256, 0, stream>>>(Wo, WoT);
    encode_kernel<<<NPOS, 256, 0, stream>>>(x, noise, rnd, We, pe, H);

    const int seq_per_b[3] = {20, 40, 32};
    for (int l = 0; l < 2; l++) {
        biasinit_kernel<<<NPOS, 256, 0, stream>>>(bo + (size_t)l * 3 * CDIM, Hn);
        for (int a = 0; a < 3; a++) {
            const bf16* bq = WqkvT + (size_t)(l * 3 + a) * 768 * 256;
            const bf16* bw = WoT   + (size_t)(l * 3 + a) * 256 * 256;
            for (int ch = 0; ch < c; ch++) {
                const bf16* Hc = H + (size_t)ch * mc * CDIM;
                bf16* Hnc      = Hn + (size_t)ch * mc * CDIM;
                gemm_mfma<<<dim3(768 / 128, mc / 128), 256, 0, stream>>>(
                    Hc, CDIM, bq, QKV, 768, 0);
                attn_kernel<<<(mc / 160) * seq_per_b[a], 256, 0, stream>>>(QKV, a);
                gemm_mfma<<<dim3(256 / 128, mc / 128), 256, 0, stream>>>(
                    QKV, 768, bw, Hnc, CDIM, (a == 2) ? 2 : 1);
            }
        }
        bf16* tmp = H; H = Hn; Hn = tmp;
    }

    decode_kernel<<<NPOS / 4, 256, 0, stream>>>(H, Wd, bd, out);
}

// Round 4
// 1000.622 us; speedup vs baseline: 6.5997x; 1.2674x over previous
//
#include <hip/hip_runtime.h>
#include <hip/hip_bf16.h>
#include <math.h>

#define NPOS 81920   // 512*8*4*5
#define CDIM 256
#define SIGMA 1e-4f
#define LEAK 0.2f

typedef __hip_bfloat16 bf16;
typedef __bf16 bf16x8 __attribute__((ext_vector_type(8)));
typedef float f32x4 __attribute__((ext_vector_type(4)));

__device__ __forceinline__ float bf2f(unsigned short u) {
    return __uint_as_float(((unsigned)u) << 16);
}
__device__ __forceinline__ unsigned short f2bfu(float f) {
    bf16 h = __float2bfloat16(f);
    return *reinterpret_cast<unsigned short*>(&h);
}

// ---------------- encoder: h = tanh([x+sigma*noise, rand] @ W_enc) + pos_emb ----------------
__global__ void encode_kernel(const float* __restrict__ x, const float* __restrict__ noise,
                              const float* __restrict__ rnd, const float* __restrict__ We,
                              const float* __restrict__ pe, bf16* __restrict__ H) {
    int p = blockIdx.x;
    int c = threadIdx.x;
    float a = x[p] + SIGMA * noise[p];
    float b = rnd[p];
    float v = tanhf(a * We[c] + b * We[CDIM + c]) + pe[(p % 160) * CDIM + c];
    H[(size_t)p * CDIM + c] = __float2bfloat16(v);
}

// ---------------- bsum[l][c] = bo[l,0,c]+bo[l,1,c]+bo[l,2,c] ----------------
__global__ void bias3_kernel(const float* __restrict__ bo, float* __restrict__ bsum) {
    int l = blockIdx.x, c = threadIdx.x;
    bsum[l * CDIM + c] = bo[l * 768 + c] + bo[l * 768 + 256 + c] + bo[l * 768 + 512 + c];
}

// ---------------- weight pack: B^T bf16 ----------------
__global__ void pack_qkv_kernel(const float* __restrict__ Wq, const float* __restrict__ Wkv,
                                bf16* __restrict__ out) {
    int mat = blockIdx.x / 768;
    int n = blockIdx.x % 768;
    int k = threadIdx.x;
    float v = (n < 256) ? Wq[(size_t)mat * 65536 + (size_t)k * 256 + n]
                        : Wkv[(size_t)mat * 131072 + (size_t)k * 512 + (n - 256)];
    out[(size_t)blockIdx.x * 256 + k] = __float2bfloat16(v);
}
__global__ void pack_wo_kernel(const float* __restrict__ Wo, bf16* __restrict__ out) {
    int mat = blockIdx.x / 256;
    int n = blockIdx.x % 256;
    int k = threadIdx.x;
    out[(size_t)blockIdx.x * 256 + k] =
        __float2bfloat16(Wo[(size_t)mat * 65536 + (size_t)k * 256 + n]);
}

// ---------------- bf16 MFMA GEMM: C[M x N] (+)= A[M x 256] @ B^T[N x 256]^T ----------------
// 128x128 tile, BK=32, 256 threads (2x2 waves of 64x64), 16x16x32_bf16.
// mode: 0 = store, 1 = RMW add, 2 = RMW add + leaky-relu, 3 = store + bias[col]
__global__ __launch_bounds__(256) void gemm_mfma(const bf16* __restrict__ A, int lda,
                                                 const bf16* __restrict__ Bt,
                                                 bf16* __restrict__ C, int ldc, int mode,
                                                 const float* __restrict__ bias) {
    __shared__ __bf16 Asb[128 * 32];
    __shared__ __bf16 Bsb[128 * 32];
    int tid = threadIdx.x;
    int wave = tid >> 6, lane = tid & 63;
    int quad = lane >> 4, m = lane & 15;
    int bm = blockIdx.y * 128, bn = blockIdx.x * 128;
    int wr = (wave >> 1) * 64, wc = (wave & 1) * 64;
    f32x4 acc[4][4] = {};

    for (int k0 = 0; k0 < 256; k0 += 32) {
#pragma unroll
        for (int rep = 0; rep < 2; rep++) {
            int ch = rep * 256 + wave * 64 + lane;
            int row = ch >> 2, c16 = ch & 3;
            __builtin_amdgcn_global_load_lds(
                (const __attribute__((address_space(1))) void*)(A + (size_t)(bm + row) * lda + k0 + c16 * 8),
                (__attribute__((address_space(3))) void*)(Asb + (rep * 256 + wave * 64) * 8),
                16, 0, 0);
        }
#pragma unroll
        for (int rep = 0; rep < 2; rep++) {
            int ch = rep * 256 + wave * 64 + lane;
            int row = ch >> 2, c16 = ch & 3;
            __builtin_amdgcn_global_load_lds(
                (const __attribute__((address_space(1))) void*)(Bt + (size_t)(bn + row) * 256 + k0 + c16 * 8),
                (__attribute__((address_space(3))) void*)(Bsb + (rep * 256 + wave * 64) * 8),
                16, 0, 0);
        }
        __syncthreads();
        bf16x8 af[4], bf_[4];
#pragma unroll
        for (int i = 0; i < 4; i++)
            af[i] = *(const bf16x8*)(Asb + (wr + i * 16 + m) * 32 + quad * 8);
#pragma unroll
        for (int j = 0; j < 4; j++)
            bf_[j] = *(const bf16x8*)(Bsb + (wc + j * 16 + m) * 32 + quad * 8);
#pragma unroll
        for (int i = 0; i < 4; i++)
#pragma unroll
            for (int j = 0; j < 4; j++)
                acc[i][j] = __builtin_amdgcn_mfma_f32_16x16x32_bf16(af[i], bf_[j], acc[i][j], 0, 0, 0);
        __syncthreads();
    }

#pragma unroll
    for (int i = 0; i < 4; i++) {
#pragma unroll
        for (int j = 0; j < 4; j++) {
#pragma unroll
            for (int r = 0; r < 4; r++) {
                int row = bm + wr + i * 16 + quad * 4 + r;
                int col = bn + wc + j * 16 + m;
                size_t idx = (size_t)row * ldc + col;
                float v = acc[i][j][r];
                if (mode == 3) v += bias[col];
                if (mode == 1 || mode == 2) v += __bfloat162float(C[idx]);
                if (mode == 2) v = v >= 0.f ? v : LEAK * v;
                C[idx] = __float2bfloat16(v);
            }
        }
    }
}

// ---------------- wave-per-sequence axial attention (register-resident) ----------------
// QKV row = 768 bf16: q | k | v. Lane = head*4 + dimgroup; lane's 4 dims = 8 B chunks.
// Output written back over q slot. No LDS, no syncthreads; all loops fully unrolled.
template <int AXIS>
__global__ __launch_bounds__(256) void attn_wave(bf16* __restrict__ QKV) {
    constexpr int T      = (AXIS == 0) ? 8 : (AXIS == 1) ? 4 : 5;
    constexpr int STRIDE = (AXIS == 0) ? 20 : (AXIS == 1) ? 5 : 1;
    int wave = threadIdx.x >> 6, lane = threadIdx.x & 63;
    int seq = blockIdx.x * 4 + wave;
    int base;
    if (AXIS == 0)      { int b = seq / 20, r = seq % 20; base = b * 160 + r; }
    else if (AXIS == 1) { int b = seq / 40, r = seq % 40; base = b * 160 + (r / 5) * 20 + (r % 5); }
    else                { int b = seq / 32, r = seq % 32; base = b * 160 + r * 5; }

    float q[T][4], k[T][4], v[T][4];
#pragma unroll
    for (int t = 0; t < T; t++) {
        const unsigned short* rowp =
            (const unsigned short*)QKV + (size_t)(base + t * STRIDE) * 768 + lane * 4;
        ushort4 qu = *(const ushort4*)(rowp);
        ushort4 ku = *(const ushort4*)(rowp + 256);
        ushort4 vu = *(const ushort4*)(rowp + 512);
        q[t][0] = bf2f(qu.x); q[t][1] = bf2f(qu.y); q[t][2] = bf2f(qu.z); q[t][3] = bf2f(qu.w);
        k[t][0] = bf2f(ku.x); k[t][1] = bf2f(ku.y); k[t][2] = bf2f(ku.z); k[t][3] = bf2f(ku.w);
        v[t][0] = bf2f(vu.x); v[t][1] = bf2f(vu.y); v[t][2] = bf2f(vu.z); v[t][3] = bf2f(vu.w);
    }

#pragma unroll
    for (int t = 0; t < T; t++) {
        float sc[T];
#pragma unroll
        for (int s = 0; s < T; s++) {
            float p = q[t][0] * k[s][0] + q[t][1] * k[s][1] + q[t][2] * k[s][2] + q[t][3] * k[s][3];
            p += __shfl_xor(p, 1);
            p += __shfl_xor(p, 2);
            sc[s] = p * 0.25f;  // * DH^-0.5
        }
        float mx = sc[0];
#pragma unroll
        for (int s = 1; s < T; s++) mx = fmaxf(mx, sc[s]);
        float sum = 0.f;
#pragma unroll
        for (int s = 0; s < T; s++) { sc[s] = __expf(sc[s] - mx); sum += sc[s]; }
        float inv = 1.f / sum;
        float o0 = 0.f, o1 = 0.f, o2 = 0.f, o3 = 0.f;
#pragma unroll
        for (int s = 0; s < T; s++) {
            o0 += sc[s] * v[s][0]; o1 += sc[s] * v[s][1];
            o2 += sc[s] * v[s][2]; o3 += sc[s] * v[s][3];
        }
        ushort4 st;
        st.x = f2bfu(o0 * inv); st.y = f2bfu(o1 * inv);
        st.z = f2bfu(o2 * inv); st.w = f2bfu(o3 * inv);
        *(ushort4*)((unsigned short*)QKV + (size_t)(base + t * STRIDE) * 768 + lane * 4) = st;
    }
}

// ---------------- decoder: out = sigmoid(H @ Wd + bd) ----------------
__global__ void decode_kernel(const bf16* __restrict__ H, const float* __restrict__ Wd,
                              const float* __restrict__ bd, float* __restrict__ out) {
    int tid = threadIdx.x;
    int pos = blockIdx.x * 4 + (tid >> 6);
    int lane = tid & 63;
    float acc = 0.f;
#pragma unroll
    for (int q = 0; q < 4; q++) {
        int c = lane + q * 64;
        acc += __bfloat162float(H[(size_t)pos * CDIM + c]) * Wd[c];
    }
#pragma unroll
    for (int off = 32; off > 0; off >>= 1) acc += __shfl_down(acc, off);
    if (lane == 0) out[pos] = 1.f / (1.f + expf(-(acc + bd[0])));
}

extern "C" void kernel_launch(void* const* d_in, const int* in_sizes, int n_in,
                              void* d_out, int out_size, void* d_ws, size_t ws_size,
                              hipStream_t stream) {
    const float* x     = (const float*)d_in[0];
    const float* noise = (const float*)d_in[1];
    const float* rnd   = (const float*)d_in[2];
    const float* We    = (const float*)d_in[3];
    const float* pe    = (const float*)d_in[4];
    const float* Wq    = (const float*)d_in[5];
    const float* Wkv   = (const float*)d_in[6];
    const float* Wo    = (const float*)d_in[7];
    const float* bo    = (const float*)d_in[8];
    const float* Wd    = (const float*)d_in[9];
    const float* bd    = (const float*)d_in[10];
    float* out = (float*)d_out;

    // ws layout: H bf16 | Hn bf16 | WqkvT bf16 | WoT bf16 | bsum f32[512] | QKV bf16 (chunk)
    bf16* H     = (bf16*)d_ws;
    bf16* Hn    = H + (size_t)NPOS * CDIM;
    bf16* WqkvT = Hn + (size_t)NPOS * CDIM;
    bf16* WoT   = WqkvT + (size_t)6 * 768 * 256;
    float* bsum = (float*)(WoT + (size_t)6 * 256 * 256);
    bf16* QKV   = (bf16*)(bsum + 512);

    size_t fixed = ((size_t)NPOS * CDIM * 2 + (size_t)6 * 768 * 256 + (size_t)6 * 256 * 256) * 2
                   + 512 * 4;
    int c = 1;
    while (c < 8 && fixed + (size_t)(NPOS / c) * 768 * 2 > ws_size) c <<= 1;
    int mc = NPOS / c;  // rows per chunk: multiple of 160 and 128 for c in {1,2,4,8}

    pack_qkv_kernel<<<6 * 768, 256, 0, stream>>>(Wq, Wkv, WqkvT);
    pack_wo_kernel<<<6 * 256, 256, 0, stream>>>(Wo, WoT);
    bias3_kernel<<<2, 256, 0, stream>>>(bo, bsum);
    encode_kernel<<<NPOS, 256, 0, stream>>>(x, noise, rnd, We, pe, H);

    const int seq_per_b[3] = {20, 40, 32};
    for (int l = 0; l < 2; l++) {
        for (int a = 0; a < 3; a++) {
            const bf16* bq = WqkvT + (size_t)(l * 3 + a) * 768 * 256;
            const bf16* bw = WoT   + (size_t)(l * 3 + a) * 256 * 256;
            for (int ch = 0; ch < c; ch++) {
                const bf16* Hc = H + (size_t)ch * mc * CDIM;
                bf16* Hnc      = Hn + (size_t)ch * mc * CDIM;
                gemm_mfma<<<dim3(768 / 128, mc / 128), 256, 0, stream>>>(
                    Hc, CDIM, bq, QKV, 768, 0, nullptr);
                int nblk = (mc / 160) * seq_per_b[a] / 4;
                if (a == 0)      attn_wave<0><<<nblk, 256, 0, stream>>>(QKV);
                else if (a == 1) attn_wave<1><<<nblk, 256, 0, stream>>>(QKV);
                else             attn_wave<2><<<nblk, 256, 0, stream>>>(QKV);
                gemm_mfma<<<dim3(256 / 128, mc / 128), 256, 0, stream>>>(
                    QKV, 768, bw, Hnc, CDIM, (a == 0) ? 3 : (a == 2) ? 2 : 1,
                    bsum + l * CDIM);
            }
        }
        bf16* tmp = H; H = Hn; Hn = tmp;
    }

    decode_kernel<<<NPOS / 4, 256, 0, stream>>>(H, Wd, bd, out);
}